// Round 9
// baseline (258.104 us; speedup 1.0000x reference)
//
#include <hip/hip_runtime.h>
#include <hip/hip_bf16.h>
#include <stdint.h>

// ---------------------------------------------------------------------------
// fp32 inputs; mask int32; fp32 output. Internal pipeline bf16/f16.
// prep (LN + Wq/Wkv transposes + nullkv, ONE dispatch) -> fused QKV GEMM
//   (Q l2norm | K l2norm | V f16 transposed [b,h][d][tok], null @ col 2048)
//   -> flash attn -> WoutT transpose -> out proj GEMM.  5 dispatches.
// R18: (a) setprio REVERTED: R17 A/B showed attn 77.4->78.8 with it — our
//      4 waves/block are barrier-locked each tile (m190 lockstep regime,
//      not m191 phase-diverse): boosting MFMA waves starves staging issue.
//      (b) LN folded into prep (6->5 dispatches, ~3.5us/boundary). Block
//      order: LN rows first, weight transposes LAST -> the 6MB weight slab
//      (re-read by every QKV block) is L2-freshest at QKV start.
// R16/R17: per-role XCD-chunked tile swizzle (FETCH 195->~60MB); prep merge.
// R14/R15: BK=64 + T2 LDS swizzle + dbuf 2-phase GEMM; role-ordered QKV.
// ---------------------------------------------------------------------------

using f32x4  = __attribute__((ext_vector_type(4))) float;
using bf16x8 = __attribute__((ext_vector_type(8))) __bf16;
using f16x8  = __attribute__((ext_vector_type(8))) _Float16;
using uintv4 = __attribute__((ext_vector_type(4))) unsigned int;

__device__ __forceinline__ unsigned short f2b(float f) {
    unsigned u = __float_as_uint(f);
    u += 0x7fffu + ((u >> 16) & 1u);   // RNE
    return (unsigned short)(u >> 16);
}
__device__ __forceinline__ unsigned short f2h(float f) {   // RNE f32->f16
    return __builtin_bit_cast(unsigned short, (_Float16)f);
}
__device__ __forceinline__ f32x4 mfma16(bf16x8 a, bf16x8 b, f32x4 c) {
    return __builtin_amdgcn_mfma_f32_16x16x32_bf16(a, b, c, 0, 0, 0);
}
__device__ __forceinline__ f32x4 mfma16h(f16x8 a, f16x8 b, f32x4 c) {
    return __builtin_amdgcn_mfma_f32_16x16x32_f16(a, b, c, 0, 0, 0);
}
// packed f32x2 -> f16x2 (RTZ), returned as the raw 32-bit pattern
__device__ __forceinline__ unsigned pk16(float a, float b) {
    return __builtin_bit_cast(unsigned, __builtin_amdgcn_cvt_pkrtz(a, b));
}
// async global->LDS, 16B/lane; LDS dst = wave-uniform base + lane*16
__device__ __forceinline__ void gl_lds16(const void* g, void* l) {
    __builtin_amdgcn_global_load_lds(
        (const __attribute__((address_space(1))) unsigned int*)g,
        (__attribute__((address_space(3))) unsigned int*)l, 16, 0, 0);
}

// ------------- weight transpose + fp32->bf16: in[R][C] -> out[C][R] --------
__global__ __launch_bounds__(256) void transpose_f2b(
    const float* __restrict__ in, unsigned short* __restrict__ out,
    int R, int C)
{
    __shared__ unsigned short t[32][33];
    int tx = threadIdx.x, ty = threadIdx.y;       // (32,8)
    int c = blockIdx.x * 32 + tx;
#pragma unroll
    for (int i = 0; i < 4; ++i) {
        int r = blockIdx.y * 32 + ty + i * 8;
        t[ty + i * 8][tx] = f2b(in[(size_t)r * C + c]);
    }
    __syncthreads();
    int r2 = blockIdx.y * 32 + tx;
#pragma unroll
    for (int i = 0; i < 4; ++i) {
        int c2 = blockIdx.x * 32 + ty + i * 8;
        out[(size_t)c2 * R + r2] = t[tx][ty + i * 8];
    }
}

// ---- prep: LN (8192) + Wq/Wkv transposes (3072, LAST for L2) + nullkv -----
// bid<8192: LayerNorm row -> xn bf16. 8192..11263: Wq/Wkv transpose tile.
// 11264..11267: nullkv (k l2norm -> knull; v f16 -> VtG col 2048 + zero pad).
__global__ __launch_bounds__(256) void prep_kernel(
    const float* __restrict__ x, const float* __restrict__ gamma,
    const float* __restrict__ Wq, const float* __restrict__ Wkv,
    const float* __restrict__ null_kv, const float* __restrict__ k_scale,
    unsigned short* __restrict__ xn,
    unsigned short* __restrict__ WqkvT, unsigned short* __restrict__ knull,
    unsigned short* __restrict__ Vt)
{
    __shared__ unsigned short t[32][33];
    __shared__ float ps[4], ps2[4], sh[2];
    const int bid = blockIdx.x;
    const int flat = threadIdx.x + threadIdx.y * 32;

    if (bid < 8192) {                          // ---- LayerNorm row ----
        int row = bid, tid = flat;
        int wave = tid >> 6, lane = tid & 63;
        float4 raw = *(const float4*)(x + ((size_t)row << 10) + (tid << 2));
        float v[4] = { raw.x, raw.y, raw.z, raw.w };
        float s  = v[0] + v[1] + v[2] + v[3];
        float s2 = v[0]*v[0] + v[1]*v[1] + v[2]*v[2] + v[3]*v[3];
#pragma unroll
        for (int off = 1; off < 64; off <<= 1) {
            s  += __shfl_xor(s, off);
            s2 += __shfl_xor(s2, off);
        }
        if (lane == 0) { ps[wave] = s; ps2[wave] = s2; }
        __syncthreads();
        if (tid == 0) {
            float S  = ps[0] + ps[1] + ps[2] + ps[3];
            float S2 = ps2[0] + ps2[1] + ps2[2] + ps2[3];
            float mu  = S * (1.f / 1024.f);
            float var = S2 * (1.f / 1024.f) - mu * mu;
            sh[0] = mu; sh[1] = rsqrtf(var + 1e-5f);
        }
        __syncthreads();
        float mu = sh[0], rstd = sh[1];
        float4 g4 = *(const float4*)(gamma + (tid << 2));
        float g[4] = { g4.x, g4.y, g4.z, g4.w };
        unsigned short o[4];
#pragma unroll
        for (int i = 0; i < 4; ++i) o[i] = f2b((v[i] - mu) * rstd * g[i]);
        uint2 out;
        out.x = (unsigned)o[0] | ((unsigned)o[1] << 16);
        out.y = (unsigned)o[2] | ((unsigned)o[3] << 16);
        *(uint2*)(xn + ((size_t)row << 10) + (tid << 2)) = out;
        return;
    }

    const int bid2 = bid - 8192;
    if (bid2 < 3072) {                         // ---- weight transpose ----
        const float* in; unsigned short* out; int C, bx, by;
        if (bid2 < 1024) { in = Wq;  out = WqkvT;              C = 1024;
                           bx = bid2 & 31;  by = bid2 >> 5; }
        else             { int l = bid2 - 1024;
                           in = Wkv; out = WqkvT + (1u << 20); C = 2048;
                           bx = l & 63;     by = l >> 6; }
        int tx = threadIdx.x, ty = threadIdx.y;   // (32,8)
        int c = bx * 32 + tx;
#pragma unroll
        for (int i = 0; i < 4; ++i) {
            int r = by * 32 + ty + i * 8;
            t[ty + i * 8][tx] = f2b(in[(size_t)r * C + c]);
        }
        __syncthreads();
        int r2 = by * 32 + tx;
#pragma unroll
        for (int i = 0; i < 4; ++i) {
            int c2 = bx * 32 + ty + i * 8;
            out[(size_t)c2 * 1024 + r2] = t[tx][ty + i * 8];
        }
        return;
    }

    // ---- nullkv (4 blocks) ----
    const int nb = bid2 - 3072;
    int wave = flat >> 6, lane = flat & 63;
    int h = nb * 4 + wave;
    int idx = (h << 6) + lane;
    float kvl = null_kv[idx];
    float ss = kvl * kvl;
#pragma unroll
    for (int off = 1; off < 64; off <<= 1) ss += __shfl_xor(ss, off);
    knull[idx] = f2b(kvl * rsqrtf(ss + 1e-12f) * k_scale[lane]);
    unsigned short vn = f2h(null_kv[1024 + idx]);
#pragma unroll
    for (int b = 0; b < 4; ++b)
        Vt[((size_t)(((b << 4) + h) << 6) + lane) * 2056 + 2048] = vn;
    int tt = nb * 256 + flat;                     // 0..1023
#pragma unroll
    for (int rr = 0; rr < 4; ++rr) {
        size_t row = (size_t)tt * 4 + rr;
#pragma unroll
        for (int c = 0; c < 7; ++c)
            Vt[row * 2056 + 2049 + c] = 0;
    }
}

// ---- GEMM C=A[8192,K]*Bt[N,K]^T, 128x128 tile, BK=64, swizzled dbuf LDS --
// 2-phase: stage(next, buf^1) -> compute(buf) -> ONE barrier per K-step.
// Tile mapping: local=bid&511 rotated to swz=(local&7)*64+(local>>3) so each
// XCD owns a contiguous band of 8 m-tiles (R16). LDS [row][64] granule g at
// slot g^(row&7), staged pre-swizzled; ds_read_b128 <=2-way.
// MODE 0: role=bid>>9: 0 Q l2norm*qs*0.125*log2e -> C0; 1 K l2norm*ks -> Ck;
//         2 V raw f16 transposed -> Vout (LDS tile aliases staging smem).
// MODE 2: 512 blocks, plain f32 store -> C0.
template<int MODE>
__global__ __launch_bounds__(256, 2) void gemm_bt(
    const unsigned short* __restrict__ A,
    const unsigned short* __restrict__ Bt,
    void* __restrict__ C0,
    unsigned short* __restrict__ Ck,
    unsigned short* __restrict__ Vout,
    const float* __restrict__ qs, const float* __restrict__ ks,
    int K)
{
    __shared__ __align__(16) unsigned char smem[65536];
    __bf16* As = (__bf16*)smem;             // [2][128][64] swizzled granules
    __bf16* Bs = (__bf16*)(smem + 32768);

    int tid = threadIdx.x, lane = tid & 63, wave = tid >> 6;
    int quad = lane >> 4, l15 = lane & 15;
    const int bid = blockIdx.x;
    const int role = bid >> 9;              // 0=Q 1=K 2=V (MODE 0)
    const int local = bid & 511;
    const int swztile = ((local & 7) << 6) | (local >> 3);  // XCD-chunked
    int m0 = (swztile >> 3) * 128;
    int n0 = role * 1024 + (swztile & 7) * 128;
    int wm = (wave & 1) * 64, wn = (wave >> 1) * 64;
    f32x4 acc[4][4] = {};

    // staging: lane covers row (slab + p*8 + lane>>3), granule (lane&7);
    // source col pre-swizzled so LDS slot w holds granule w^(row&7).
    const int srow8 = lane >> 3;            // row-within-8 == (row&7)
    const int w7    = lane & 7;
    const int swz   = ((w7 ^ srow8) << 3);  // halfs
    const unsigned short* gA = A  + (size_t)(m0 + wave * 32 + srow8) * K + swz;
    const unsigned short* gB = Bt + (size_t)(n0 + wave * 32 + srow8) * K + swz;
    const size_t r8 = (size_t)8 * K;

    auto stage = [&](int bf) {
        __bf16* Ab = As + bf * 8192;
        __bf16* Bb = Bs + bf * 8192;
#pragma unroll
        for (int p = 0; p < 4; ++p)
            gl_lds16(gA + p * r8, &Ab[(wave * 32 + p * 8) * 64]);
#pragma unroll
        for (int p = 0; p < 4; ++p)
            gl_lds16(gB + p * r8, &Bb[(wave * 32 + p * 8) * 64]);
        gA += 64; gB += 64;
    };

    stage(0);
    __syncthreads();                        // tile 0 resident
    const int nsteps = K >> 6;
    for (int s = 0; s < nsteps; ++s) {
        const int cur = s & 1;
        if (s + 1 < nsteps) stage(cur ^ 1); // prefetch flies under compute
        const __bf16* Ab = As + cur * 8192;
        const __bf16* Bb = Bs + cur * 8192;
#pragma unroll
        for (int kk = 0; kk < 2; ++kk) {
            bf16x8 af[4], bfv[4];
#pragma unroll
            for (int i = 0; i < 4; ++i) {
                int row = wm + i * 16 + l15;
                int g = ((kk << 2) + quad) ^ (l15 & 7);
                af[i] = *(const bf16x8*)&Ab[row * 64 + (g << 3)];
            }
#pragma unroll
            for (int j = 0; j < 4; ++j) {
                int row = wn + j * 16 + l15;
                int g = ((kk << 2) + quad) ^ (l15 & 7);
                bfv[j] = *(const bf16x8*)&Bb[row * 64 + (g << 3)];
            }
#pragma unroll
            for (int i = 0; i < 4; ++i)
#pragma unroll
                for (int j = 0; j < 4; ++j)
                    acc[i][j] = mfma16(af[i], bfv[j], acc[i][j]);
        }
        __syncthreads();  // drains prefetch (flew under MFMA) + frees cur
    }

    if (MODE == 2) {
#pragma unroll
        for (int i = 0; i < 4; ++i)
#pragma unroll
            for (int j = 0; j < 4; ++j) {
                int row = m0 + wm + i * 16 + quad * 4;
                int col = n0 + wn + j * 16 + l15;
                size_t base = (size_t)row * 1024 + col;
#pragma unroll
                for (int r = 0; r < 4; ++r)
                    ((float*)C0)[base + (size_t)r * 1024] = acc[i][j][r];
            }
        return;
    }

    // ----- fused QKV epilogues (wave's 64 cols = one head) -----
    if (n0 >= 2048) {
        // V: per-wave 64x64 (tok x d) -> LDS transpose (aliases staging smem;
        // safe: final K-loop barrier drained all reads) -> uint2 stores.
        unsigned short* tileL = (unsigned short*)smem + wave * 4096;
        int hv = (n0 + wn - 2048) >> 6;
        int bidx = m0 >> 11;                        // block never straddles
        int tok0w = (m0 + wm) & 2047;
        size_t vbase = (size_t)((((bidx << 4) + hv) << 6)) * 2056;
#pragma unroll
        for (int i = 0; i < 4; ++i)
#pragma unroll
            for (int j = 0; j < 4; ++j) {
                int d = j * 16 + l15;
                int tk = (i * 16 + quad * 4) ^ ((d & 7) << 3);
                unsigned u01 = (unsigned)f2h(acc[i][j][0])
                             | ((unsigned)f2h(acc[i][j][1]) << 16);
                unsigned u23 = (unsigned)f2h(acc[i][j][2])
                             | ((unsigned)f2h(acc[i][j][3]) << 16);
                *(unsigned*)&tileL[d * 64 + tk]     = u01;
                *(unsigned*)&tileL[d * 64 + tk + 2] = u23;
            }
        // same-wave read-out (compiler orders via lgkmcnt)
#pragma unroll
        for (int rrr = 0; rrr < 16; ++rrr) {
            int d = rrr * 4 + quad;
            uint2 val = *(const uint2*)
                &tileL[d * 64 + ((l15 * 4) ^ ((d & 7) << 3))];
            *(uint2*)(Vout + vbase + (size_t)d * 2056 + tok0w + l15 * 4) = val;
        }
        return;
    }

    const bool isQ = (n0 < 1024);
    float sc[4];
#pragma unroll
    for (int j = 0; j < 4; ++j) {
        float s = isQ ? qs[j * 16 + l15] : ks[j * 16 + l15];
        sc[j] = isQ ? s * (0.125f * 1.44269504088896f) : s;
    }
    unsigned short* outp = isQ ? (unsigned short*)C0 : Ck;
    const int coln0 = isQ ? n0 : (n0 - 1024);
#pragma unroll
    for (int i = 0; i < 4; ++i)
#pragma unroll
        for (int r = 0; r < 4; ++r) {
            float ss = 0.f;
#pragma unroll
            for (int j = 0; j < 4; ++j) ss += acc[i][j][r] * acc[i][j][r];
            ss += __shfl_xor(ss, 1); ss += __shfl_xor(ss, 2);
            ss += __shfl_xor(ss, 4); ss += __shfl_xor(ss, 8);
            float mul = rsqrtf(ss + 1e-12f);
            size_t rowbase = (size_t)(m0 + wm + i * 16 + quad * 4 + r) * 1024
                           + coln0 + wn + l15;
#pragma unroll
            for (int j = 0; j < 4; ++j) {
                float v = acc[i][j][r];
                outp[rowbase + j * 16] = f2b(v * mul * sc[j]);
            }
        }
}

// ---------------- attention: BM=128 (4 waves x 32 rows), BT=64 tokens ------
// (R13 structure; R18 reverts R17's setprio — measured −1.4us regression)
__global__ __launch_bounds__(256, 4) void attn_kernel(
    const unsigned short* __restrict__ qn,    // [B*2048,1024] l2norm*qs*log2e/8
    const unsigned short* __restrict__ kvK,   // [B*2048,1024] k bf16 (l2norm)
    const unsigned short* __restrict__ knull, // [16*64] bf16
    const unsigned short* __restrict__ Vt,    // [64bh][64d][2056tok] f16
    const int* __restrict__ mask,             // [B*2048]
    unsigned short* __restrict__ ao)          // [B*2048,1024]
{
    __shared__ __bf16    Kt[2][64 * 64];
    __shared__ _Float16  Vl[2][64 * 64];
    __shared__ __align__(16) float biasLds[2][64];

    const int tid = threadIdx.x, lane = tid & 63, wave = tid >> 6;
    const int quad = lane >> 4, l15 = lane & 15;
    const int bh = blockIdx.x;                 // (b,h): K/V sharers same XCD
    const int b = bh >> 4, h = bh & 15;
    const int mbase = blockIdx.y * 128 + wave * 32;
    const size_t rowoff = (size_t)b * 2048;

    bf16x8 qf[2][2];                           // B-operand fragments
#pragma unroll
    for (int rg = 0; rg < 2; ++rg)
#pragma unroll
        for (int ks = 0; ks < 2; ++ks)
            qf[rg][ks] = *(const bf16x8*)
                &qn[((rowoff + mbase + rg * 16 + l15) << 10) + (h << 6) + ks * 32 + quad * 8];

    const int t8  = lane >> 3;
    const int w7  = lane & 7;
    const int ksc = (w7 ^ t8) << 3;            // (r&7)==t8 since base%8==0
    const size_t vrow0 = ((size_t)bh << 6);    // first VtG row of this (b,h)

    const int r0v = wave * 16 + t8;            // LDS row (p=0) = V d-row
    const int r1v = wave * 16 + 8 + t8;        // LDS row (p=1)
    auto Tof = [](int r) {
        return ((r >> 5) << 5) | (((r >> 2) & 3) << 3)
             | (((r >> 4) & 1) << 2) | (r & 3);
    };
    const int T0 = Tof(r0v), T1 = Tof(r1v);    // T1 != 0 always

    // strength-reduced staging pointers (point at NEXT tile to issue)
    const unsigned short* kp0 = kvK + ((rowoff + T0) << 10) + (h << 6) + ksc;
    const unsigned short* kp1 = kvK + ((rowoff + T1) << 10) + (h << 6) + ksc;
    const unsigned short* vp0 = Vt + (vrow0 + r0v) * 2056 + ((w7 ^ t8) << 3);
    const unsigned short* vp1 = Vt + (vrow0 + r1v) * 2056 + ((w7 ^ t8) << 3);

    auto issueFast = [&](int bf) {
        gl_lds16(kp0, &Kt[bf][(wave * 16) * 64]);
        gl_lds16(kp1, &Kt[bf][(wave * 16 + 8) * 64]);
        gl_lds16(vp0, &Vl[bf][(wave * 16) * 64]);
        gl_lds16(vp1, &Vl[bf][(wave * 16 + 8) * 64]);
        kp0 += 65536; kp1 += 65536;            // 64 tokens * 1024 halfs
        vp0 += 64; vp1 += 64;                  // 8 granules
    };
    auto issue32 = [&](int bf) {               // tokens 2048..2111
        const unsigned short* kc =
            kvK + ((rowoff + 2047) << 10) + (h << 6) + ksc;   // finite clamp
        const unsigned short* s0 = (T0 == 0) ? knull + (h << 6) + ksc : kc;
        gl_lds16(s0, &Kt[bf][(wave * 16) * 64]);
        gl_lds16(kc, &Kt[bf][(wave * 16 + 8) * 64]);
        gl_lds16(Vt + (vrow0 + r0v) * 2056 + 2048, &Vl[bf][(wave * 16) * 64]);
        gl_lds16(Vt + (vrow0 + r1v) * 2056 + 2048, &Vl[bf][(wave * 16 + 8) * 64]);
    };
    auto biasFor = [&](int nt) -> float {      // wave 0 only
        int j = (nt << 6) + lane;
        float bv = -512.f;
        if (j < 2048) { if (mask[(b << 11) + j] != 0) bv = 0.f; }
        else if (j == 2048) bv = 0.f;
        return bv;
    };

    const uintv4 onesu = { 0x3c003c00u, 0x3c003c00u, 0x3c003c00u, 0x3c003c00u };
    const f16x8 ones = __builtin_bit_cast(f16x8, onesu);

    f32x4 O[2][4] = {};
    f32x4 rsacc[2] = {};

    issueFast(0);
    float bcur = 0.f;
    if (wave == 0) bcur = biasFor(0);

    for (int nt = 0; nt < 33; ++nt) {
        const int buf = nt & 1;
        if (wave == 0) biasLds[buf][lane] = bcur;
        __syncthreads();   // drains gl_lds(nt); bias(nt) visible; prev buf free
        if (nt < 31) {     // issue AFTER barrier: overlaps compute below
            issueFast(buf ^ 1);
            if (wave == 0) bcur = biasFor(nt + 1);
        } else if (nt == 31) {
            issue32(buf ^ 1);
            if (wave == 0) bcur = biasFor(32);
        }

#pragma unroll
        for (int g = 0; g < 2; ++g) {
            // --- QK^T: only one kf pair (8 VGPRs) live at a time ---
            float4 b0 = *(const float4*)&biasLds[buf][(g << 5) + (quad << 3)];
            float4 b1 = *(const float4*)&biasLds[buf][(g << 5) + (quad << 3) + 4];
            f32x4 s[2][2];
#pragma unroll
            for (int rg = 0; rg < 2; ++rg) {
                s[rg][0] = f32x4{ b0.x, b0.y, b0.z, b0.w };
                s[rg][1] = f32x4{ b1.x, b1.y, b1.z, b1.w };
            }
#pragma unroll
            for (int t = 0; t < 2; ++t) {
                const __bf16* kb = &Kt[buf][((g * 2 + t) * 16 + l15) * 64];
                bf16x8 k0 = *(const bf16x8*)&kb[(quad ^ (l15 & 7)) << 3];
                bf16x8 k1 = *(const bf16x8*)&kb[((4 + quad) ^ (l15 & 7)) << 3];
#pragma unroll
                for (int rg = 0; rg < 2; ++rg) {
                    s[rg][t] = mfma16(k0, qf[rg][0], s[rg][t]);
                    s[rg][t] = mfma16(k1, qf[rg][1], s[rg][t]);
                }
            }
            // --- V fragments: one b128 each, XOR-swizzled slot ---
            f16x8 vf8[4];
#pragma unroll
            for (int dt = 0; dt < 4; ++dt)
                vf8[dt] = *(const f16x8*)
                    &Vl[buf][(dt * 16 + l15) * 64
                             + ((((g << 2) + quad) ^ (l15 & 7)) << 3)];
            // --- exp2 + pack + PV (+ denominator via ones-MFMA) ---
#pragma unroll
            for (int rg = 0; rg < 2; ++rg) {
                float e0 = __builtin_amdgcn_exp2f(s[rg][0][0]);
                float e1 = __builtin_amdgcn_exp2f(s[rg][0][1]);
                float e2 = __builtin_amdgcn_exp2f(s[rg][0][2]);
                float e3 = __builtin_amdgcn_exp2f(s[rg][0][3]);
                float e4 = __builtin_amdgcn_exp2f(s[rg][1][0]);
                float e5 = __builtin_amdgcn_exp2f(s[rg][1][1]);
                float e6 = __builtin_amdgcn_exp2f(s[rg][1][2]);
                float e7 = __builtin_amdgcn_exp2f(s[rg][1][3]);
                uintv4 pu = { pk16(e0, e1), pk16(e2, e3),
                              pk16(e4, e5), pk16(e6, e7) };
                f16x8 p = __builtin_bit_cast(f16x8, pu);
                rsacc[rg] = mfma16h(p, ones, rsacc[rg]);
#pragma unroll
                for (int dt = 0; dt < 4; ++dt)
                    O[rg][dt] = mfma16h(p, vf8[dt], O[rg][dt]);
            }
        }
    }

    // rsacc[rg][r] = denom for q-row rg*16 + quad*4 + r (same lane as O rows)
#pragma unroll
    for (int rg = 0; rg < 2; ++rg) {
        float inv[4];
#pragma unroll
        for (int r = 0; r < 4; ++r) inv[r] = 1.f / rsacc[rg][r];
#pragma unroll
        for (int dt = 0; dt < 4; ++dt) {
            size_t base = ((rowoff + mbase + rg * 16 + quad * 4) << 10)
                        + (h << 6) + dt * 16 + l15;
#pragma unroll
            for (int r = 0; r < 4; ++r)
                ao[base + ((size_t)r << 10)] = f2b(O[rg][dt][r] * inv[r]);
        }
    }
}

// ---------------------------------------------------------------------------
extern "C" void kernel_launch(void* const* d_in, const int* in_sizes, int n_in,
                              void* d_out, int out_size, void* d_ws, size_t ws_size,
                              hipStream_t stream)
{
    const float* x       = (const float*)d_in[0];
    const int*   mask    = (const int*)d_in[1];
    const float* gamma   = (const float*)d_in[2];
    const float* null_kv = (const float*)d_in[3];
    const float* Wq      = (const float*)d_in[4];
    const float* Wkv     = (const float*)d_in[5];
    const float* q_scale = (const float*)d_in[6];
    const float* k_scale = (const float*)d_in[7];
    const float* Wout    = (const float*)d_in[8];

    // Workspace map (~70.07 MiB; ao aliases xn; WoutT lives in the dead q
    // buffer, written by a transpose launched AFTER attn):
    //   0        xn/ao    16 MiB
    //   16 MiB   q        16 MiB   (post-attn: first 2 MiB reused as WoutT)
    //   32 MiB   kvK      16 MiB   [tok][1024] bf16
    //   48 MiB   VtG      16.0625 MiB = 4096 rows * 4112 B ([bh][d][2056] f16)
    //   +VtG     WqkvT    6 MiB    [3072][1024] bf16 (Wq rows 0..1023,
    //                              Wkv K rows 1024..2047, V rows 2048..3071)
    //   +6 MiB   knull    2 KiB
    char* ws = (char*)d_ws;
    const size_t VTG_OFF   = (size_t)48u << 20;
    const size_t VTG_SIZE  = (size_t)4096 * 4112;
    const size_t WQKV_OFF  = VTG_OFF + VTG_SIZE;
    const size_t WQKV_SIZE = (size_t)3072 * 1024 * 2;
    unsigned short* xn    = (unsigned short*)(ws);
    unsigned short* ao    = xn;                                    // reuse
    unsigned short* q     = (unsigned short*)(ws + ((size_t)16u << 20));
    unsigned short* WoutT = q;                                     // post-attn
    unsigned short* kvK   = (unsigned short*)(ws + ((size_t)32u << 20));
    unsigned short* VtG   = (unsigned short*)(ws + VTG_OFF);
    unsigned short* WqkvT = (unsigned short*)(ws + WQKV_OFF);
    unsigned short* knull = (unsigned short*)(ws + WQKV_OFF + WQKV_SIZE);

    // prep: LN (first) + Wq/Wkv transposes (last, L2-hot for QKV) + nullkv
    prep_kernel<<<dim3(11268), dim3(32, 8), 0, stream>>>(
        x, gamma, Wq, Wkv, null_kv, k_scale, xn, WqkvT, knull, VtG);

    // fused QKV projection, role-ordered 1-D grid with per-role XCD-chunked
    // tile swizzle: Q (0..511) first, K, then V last -> K/V freshest for attn
    gemm_bt<0><<<dim3(1536), 256, 0, stream>>>(xn, WqkvT, q, kvK, VtG,
                                               q_scale, k_scale, 1024);

    attn_kernel<<<dim3(64, 16), 256, 0, stream>>>(q, kvK, knull, VtG, mask, ao);

    // q is dead now; put WoutT there and run the out-projection
    transpose_f2b<<<dim3(32, 32), dim3(32, 8), 0, stream>>>(Wout, WoutT, 1024, 1024);

    gemm_bt<2><<<dim3(512), 256, 0, stream>>>(ao, WoutT, d_out, nullptr, nullptr,
                                              nullptr, nullptr, 1024);
}

// Round 10
// 255.277 us; speedup vs baseline: 1.0111x; 1.0111x over previous
//
#include <hip/hip_runtime.h>
#include <hip/hip_bf16.h>
#include <stdint.h>

// ---------------------------------------------------------------------------
// fp32 inputs; mask int32; fp32 output. Internal pipeline bf16/f16.
// prep (LN + Wq/Wkv transposes + nullkv, ONE dispatch) -> fused QKV GEMM
//   (Q l2norm | K l2norm | V f16 transposed [b,h][d][tok], null @ col 2048)
//   -> flash attn -> WoutT transpose -> out proj GEMM.  5 dispatches.
// R19: GEMM K-loop converted to COUNTED vmcnt (T4). The old __syncthreads
//      emitted s_waitcnt vmcnt(0): it drained the 8 prefetch loads issued
//      THIS iteration (only ~500cyc in flight -> ~300-400cyc HBM-miss stall
//      per K-step). Now: stage(next) -> s_waitcnt vmcnt(8) (waits ONLY the
//      old tile, in flight a full iteration) -> s_barrier -> sched_barrier(0)
//      (rule #18 fence) -> compute -> raw s_barrier (no drain; 8 loads fly
//      across). Per-wave vmcnt(8)+barrier makes the old tile visible to all
//      waves (each wave stages+tracks its own slab). Uniform control flow ->
//      raw barrier safe. attn untouched (R16-R18 deltas were noise-band).
// R18: LN folded into prep (5 dispatches); setprio verdict: noise, reverted.
// R16: per-role XCD-chunked tile swizzle (FETCH 195->~60MB).
// R14/R15: BK=64 + T2 LDS swizzle + dbuf 2-phase GEMM; role-ordered QKV.
// ---------------------------------------------------------------------------

using f32x4  = __attribute__((ext_vector_type(4))) float;
using bf16x8 = __attribute__((ext_vector_type(8))) __bf16;
using f16x8  = __attribute__((ext_vector_type(8))) _Float16;
using uintv4 = __attribute__((ext_vector_type(4))) unsigned int;

__device__ __forceinline__ unsigned short f2b(float f) {
    unsigned u = __float_as_uint(f);
    u += 0x7fffu + ((u >> 16) & 1u);   // RNE
    return (unsigned short)(u >> 16);
}
__device__ __forceinline__ unsigned short f2h(float f) {   // RNE f32->f16
    return __builtin_bit_cast(unsigned short, (_Float16)f);
}
__device__ __forceinline__ f32x4 mfma16(bf16x8 a, bf16x8 b, f32x4 c) {
    return __builtin_amdgcn_mfma_f32_16x16x32_bf16(a, b, c, 0, 0, 0);
}
__device__ __forceinline__ f32x4 mfma16h(f16x8 a, f16x8 b, f32x4 c) {
    return __builtin_amdgcn_mfma_f32_16x16x32_f16(a, b, c, 0, 0, 0);
}
// packed f32x2 -> f16x2 (RTZ), returned as the raw 32-bit pattern
__device__ __forceinline__ unsigned pk16(float a, float b) {
    return __builtin_bit_cast(unsigned, __builtin_amdgcn_cvt_pkrtz(a, b));
}
// async global->LDS, 16B/lane; LDS dst = wave-uniform base + lane*16
__device__ __forceinline__ void gl_lds16(const void* g, void* l) {
    __builtin_amdgcn_global_load_lds(
        (const __attribute__((address_space(1))) unsigned int*)g,
        (__attribute__((address_space(3))) unsigned int*)l, 16, 0, 0);
}

// ------------- weight transpose + fp32->bf16: in[R][C] -> out[C][R] --------
__global__ __launch_bounds__(256) void transpose_f2b(
    const float* __restrict__ in, unsigned short* __restrict__ out,
    int R, int C)
{
    __shared__ unsigned short t[32][33];
    int tx = threadIdx.x, ty = threadIdx.y;       // (32,8)
    int c = blockIdx.x * 32 + tx;
#pragma unroll
    for (int i = 0; i < 4; ++i) {
        int r = blockIdx.y * 32 + ty + i * 8;
        t[ty + i * 8][tx] = f2b(in[(size_t)r * C + c]);
    }
    __syncthreads();
    int r2 = blockIdx.y * 32 + tx;
#pragma unroll
    for (int i = 0; i < 4; ++i) {
        int c2 = blockIdx.x * 32 + ty + i * 8;
        out[(size_t)c2 * R + r2] = t[tx][ty + i * 8];
    }
}

// ---- prep: LN (8192) + Wq/Wkv transposes (3072, LAST for L2) + nullkv -----
// bid<8192: LayerNorm row -> xn bf16. 8192..11263: Wq/Wkv transpose tile.
// 11264..11267: nullkv (k l2norm -> knull; v f16 -> VtG col 2048 + zero pad).
__global__ __launch_bounds__(256) void prep_kernel(
    const float* __restrict__ x, const float* __restrict__ gamma,
    const float* __restrict__ Wq, const float* __restrict__ Wkv,
    const float* __restrict__ null_kv, const float* __restrict__ k_scale,
    unsigned short* __restrict__ xn,
    unsigned short* __restrict__ WqkvT, unsigned short* __restrict__ knull,
    unsigned short* __restrict__ Vt)
{
    __shared__ unsigned short t[32][33];
    __shared__ float ps[4], ps2[4], sh[2];
    const int bid = blockIdx.x;
    const int flat = threadIdx.x + threadIdx.y * 32;

    if (bid < 8192) {                          // ---- LayerNorm row ----
        int row = bid, tid = flat;
        int wave = tid >> 6, lane = tid & 63;
        float4 raw = *(const float4*)(x + ((size_t)row << 10) + (tid << 2));
        float v[4] = { raw.x, raw.y, raw.z, raw.w };
        float s  = v[0] + v[1] + v[2] + v[3];
        float s2 = v[0]*v[0] + v[1]*v[1] + v[2]*v[2] + v[3]*v[3];
#pragma unroll
        for (int off = 1; off < 64; off <<= 1) {
            s  += __shfl_xor(s, off);
            s2 += __shfl_xor(s2, off);
        }
        if (lane == 0) { ps[wave] = s; ps2[wave] = s2; }
        __syncthreads();
        if (tid == 0) {
            float S  = ps[0] + ps[1] + ps[2] + ps[3];
            float S2 = ps2[0] + ps2[1] + ps2[2] + ps2[3];
            float mu  = S * (1.f / 1024.f);
            float var = S2 * (1.f / 1024.f) - mu * mu;
            sh[0] = mu; sh[1] = rsqrtf(var + 1e-5f);
        }
        __syncthreads();
        float mu = sh[0], rstd = sh[1];
        float4 g4 = *(const float4*)(gamma + (tid << 2));
        float g[4] = { g4.x, g4.y, g4.z, g4.w };
        unsigned short o[4];
#pragma unroll
        for (int i = 0; i < 4; ++i) o[i] = f2b((v[i] - mu) * rstd * g[i]);
        uint2 out;
        out.x = (unsigned)o[0] | ((unsigned)o[1] << 16);
        out.y = (unsigned)o[2] | ((unsigned)o[3] << 16);
        *(uint2*)(xn + ((size_t)row << 10) + (tid << 2)) = out;
        return;
    }

    const int bid2 = bid - 8192;
    if (bid2 < 3072) {                         // ---- weight transpose ----
        const float* in; unsigned short* out; int C, bx, by;
        if (bid2 < 1024) { in = Wq;  out = WqkvT;              C = 1024;
                           bx = bid2 & 31;  by = bid2 >> 5; }
        else             { int l = bid2 - 1024;
                           in = Wkv; out = WqkvT + (1u << 20); C = 2048;
                           bx = l & 63;     by = l >> 6; }
        int tx = threadIdx.x, ty = threadIdx.y;   // (32,8)
        int c = bx * 32 + tx;
#pragma unroll
        for (int i = 0; i < 4; ++i) {
            int r = by * 32 + ty + i * 8;
            t[ty + i * 8][tx] = f2b(in[(size_t)r * C + c]);
        }
        __syncthreads();
        int r2 = by * 32 + tx;
#pragma unroll
        for (int i = 0; i < 4; ++i) {
            int c2 = bx * 32 + ty + i * 8;
            out[(size_t)c2 * 1024 + r2] = t[tx][ty + i * 8];
        }
        return;
    }

    // ---- nullkv (4 blocks) ----
    const int nb = bid2 - 3072;
    int wave = flat >> 6, lane = flat & 63;
    int h = nb * 4 + wave;
    int idx = (h << 6) + lane;
    float kvl = null_kv[idx];
    float ss = kvl * kvl;
#pragma unroll
    for (int off = 1; off < 64; off <<= 1) ss += __shfl_xor(ss, off);
    knull[idx] = f2b(kvl * rsqrtf(ss + 1e-12f) * k_scale[lane]);
    unsigned short vn = f2h(null_kv[1024 + idx]);
#pragma unroll
    for (int b = 0; b < 4; ++b)
        Vt[((size_t)(((b << 4) + h) << 6) + lane) * 2056 + 2048] = vn;
    int tt = nb * 256 + flat;                     // 0..1023
#pragma unroll
    for (int rr = 0; rr < 4; ++rr) {
        size_t row = (size_t)tt * 4 + rr;
#pragma unroll
        for (int c = 0; c < 7; ++c)
            Vt[row * 2056 + 2049 + c] = 0;
    }
}

// ---- GEMM C=A[8192,K]*Bt[N,K]^T, 128x128 tile, BK=64, swizzled dbuf LDS --
// 2-phase COUNTED-vmcnt pipeline (R19):
//   stage(next) -> vmcnt(8) [old tile only] -> s_barrier -> sched_barrier(0)
//   -> compute -> raw s_barrier (8 prefetch loads stay in flight).
// Tile mapping: local=bid&511 rotated to swz=(local&7)*64+(local>>3) so each
// XCD owns a contiguous band of 8 m-tiles (R16). LDS [row][64] granule g at
// slot g^(row&7), staged pre-swizzled; ds_read_b128 <=2-way.
// MODE 0: role=bid>>9: 0 Q l2norm*qs*0.125*log2e -> C0; 1 K l2norm*ks -> Ck;
//         2 V raw f16 transposed -> Vout (LDS tile aliases staging smem).
// MODE 2: 512 blocks, plain f32 store -> C0.
template<int MODE>
__global__ __launch_bounds__(256, 2) void gemm_bt(
    const unsigned short* __restrict__ A,
    const unsigned short* __restrict__ Bt,
    void* __restrict__ C0,
    unsigned short* __restrict__ Ck,
    unsigned short* __restrict__ Vout,
    const float* __restrict__ qs, const float* __restrict__ ks,
    int K)
{
    __shared__ __align__(16) unsigned char smem[65536];
    __bf16* As = (__bf16*)smem;             // [2][128][64] swizzled granules
    __bf16* Bs = (__bf16*)(smem + 32768);

    int tid = threadIdx.x, lane = tid & 63, wave = tid >> 6;
    int quad = lane >> 4, l15 = lane & 15;
    const int bid = blockIdx.x;
    const int role = bid >> 9;              // 0=Q 1=K 2=V (MODE 0)
    const int local = bid & 511;
    const int swztile = ((local & 7) << 6) | (local >> 3);  // XCD-chunked
    int m0 = (swztile >> 3) * 128;
    int n0 = role * 1024 + (swztile & 7) * 128;
    int wm = (wave & 1) * 64, wn = (wave >> 1) * 64;
    f32x4 acc[4][4] = {};

    // staging: lane covers row (slab + p*8 + lane>>3), granule (lane&7);
    // source col pre-swizzled so LDS slot w holds granule w^(row&7).
    const int srow8 = lane >> 3;            // row-within-8 == (row&7)
    const int w7    = lane & 7;
    const int swz   = ((w7 ^ srow8) << 3);  // halfs
    const unsigned short* gA = A  + (size_t)(m0 + wave * 32 + srow8) * K + swz;
    const unsigned short* gB = Bt + (size_t)(n0 + wave * 32 + srow8) * K + swz;
    const size_t r8 = (size_t)8 * K;

    auto stage = [&](int bf) {              // 8 gl_lds per wave
        __bf16* Ab = As + bf * 8192;
        __bf16* Bb = Bs + bf * 8192;
#pragma unroll
        for (int p = 0; p < 4; ++p)
            gl_lds16(gA + p * r8, &Ab[(wave * 32 + p * 8) * 64]);
#pragma unroll
        for (int p = 0; p < 4; ++p)
            gl_lds16(gB + p * r8, &Bb[(wave * 32 + p * 8) * 64]);
        gA += 64; gB += 64;
    };

    stage(0);                               // 8 loads in flight
    const int nsteps = K >> 6;
    for (int s = 0; s < nsteps; ++s) {
        const int cur = s & 1;
        if (s + 1 < nsteps) {
            stage(cur ^ 1);                 // 16 outstanding
            asm volatile("s_waitcnt vmcnt(8)" ::: "memory");  // old tile only
        } else {
            asm volatile("s_waitcnt vmcnt(0)" ::: "memory");  // final drain
        }
        __builtin_amdgcn_s_barrier();       // tile cur visible to all waves
        __builtin_amdgcn_sched_barrier(0);  // no ds_read hoists above (r#18)
        const __bf16* Ab = As + cur * 8192;
        const __bf16* Bb = Bs + cur * 8192;
#pragma unroll
        for (int kk = 0; kk < 2; ++kk) {
            bf16x8 af[4], bfv[4];
#pragma unroll
            for (int i = 0; i < 4; ++i) {
                int row = wm + i * 16 + l15;
                int g = ((kk << 2) + quad) ^ (l15 & 7);
                af[i] = *(const bf16x8*)&Ab[row * 64 + (g << 3)];
            }
#pragma unroll
            for (int j = 0; j < 4; ++j) {
                int row = wn + j * 16 + l15;
                int g = ((kk << 2) + quad) ^ (l15 & 7);
                bfv[j] = *(const bf16x8*)&Bb[row * 64 + (g << 3)];
            }
#pragma unroll
            for (int i = 0; i < 4; ++i)
#pragma unroll
                for (int j = 0; j < 4; ++j)
                    acc[i][j] = mfma16(af[i], bfv[j], acc[i][j]);
        }
        __builtin_amdgcn_sched_barrier(0);  // no ds_read sinks below
        __builtin_amdgcn_s_barrier();       // readers done before overwrite;
    }                                       // prefetch loads fly across (raw)

    if (MODE == 2) {
#pragma unroll
        for (int i = 0; i < 4; ++i)
#pragma unroll
            for (int j = 0; j < 4; ++j) {
                int row = m0 + wm + i * 16 + quad * 4;
                int col = n0 + wn + j * 16 + l15;
                size_t base = (size_t)row * 1024 + col;
#pragma unroll
                for (int r = 0; r < 4; ++r)
                    ((float*)C0)[base + (size_t)r * 1024] = acc[i][j][r];
            }
        return;
    }

    // ----- fused QKV epilogues (wave's 64 cols = one head) -----
    if (n0 >= 2048) {
        // V: per-wave 64x64 (tok x d) -> LDS transpose (aliases staging smem;
        // safe: final K-loop barrier drained all reads) -> uint2 stores.
        unsigned short* tileL = (unsigned short*)smem + wave * 4096;
        int hv = (n0 + wn - 2048) >> 6;
        int bidx = m0 >> 11;                        // block never straddles
        int tok0w = (m0 + wm) & 2047;
        size_t vbase = (size_t)((((bidx << 4) + hv) << 6)) * 2056;
#pragma unroll
        for (int i = 0; i < 4; ++i)
#pragma unroll
            for (int j = 0; j < 4; ++j) {
                int d = j * 16 + l15;
                int tk = (i * 16 + quad * 4) ^ ((d & 7) << 3);
                unsigned u01 = (unsigned)f2h(acc[i][j][0])
                             | ((unsigned)f2h(acc[i][j][1]) << 16);
                unsigned u23 = (unsigned)f2h(acc[i][j][2])
                             | ((unsigned)f2h(acc[i][j][3]) << 16);
                *(unsigned*)&tileL[d * 64 + tk]     = u01;
                *(unsigned*)&tileL[d * 64 + tk + 2] = u23;
            }
        // same-wave read-out (compiler orders via lgkmcnt)
#pragma unroll
        for (int rrr = 0; rrr < 16; ++rrr) {
            int d = rrr * 4 + quad;
            uint2 val = *(const uint2*)
                &tileL[d * 64 + ((l15 * 4) ^ ((d & 7) << 3))];
            *(uint2*)(Vout + vbase + (size_t)d * 2056 + tok0w + l15 * 4) = val;
        }
        return;
    }

    const bool isQ = (n0 < 1024);
    float sc[4];
#pragma unroll
    for (int j = 0; j < 4; ++j) {
        float s = isQ ? qs[j * 16 + l15] : ks[j * 16 + l15];
        sc[j] = isQ ? s * (0.125f * 1.44269504088896f) : s;
    }
    unsigned short* outp = isQ ? (unsigned short*)C0 : Ck;
    const int coln0 = isQ ? n0 : (n0 - 1024);
#pragma unroll
    for (int i = 0; i < 4; ++i)
#pragma unroll
        for (int r = 0; r < 4; ++r) {
            float ss = 0.f;
#pragma unroll
            for (int j = 0; j < 4; ++j) ss += acc[i][j][r] * acc[i][j][r];
            ss += __shfl_xor(ss, 1); ss += __shfl_xor(ss, 2);
            ss += __shfl_xor(ss, 4); ss += __shfl_xor(ss, 8);
            float mul = rsqrtf(ss + 1e-12f);
            size_t rowbase = (size_t)(m0 + wm + i * 16 + quad * 4 + r) * 1024
                           + coln0 + wn + l15;
#pragma unroll
            for (int j = 0; j < 4; ++j) {
                float v = acc[i][j][r];
                outp[rowbase + j * 16] = f2b(v * mul * sc[j]);
            }
        }
}

// ---------------- attention: BM=128 (4 waves x 32 rows), BT=64 tokens ------
// (R13 structure, untouched — R16-R18 deltas were within the noise band)
__global__ __launch_bounds__(256, 4) void attn_kernel(
    const unsigned short* __restrict__ qn,    // [B*2048,1024] l2norm*qs*log2e/8
    const unsigned short* __restrict__ kvK,   // [B*2048,1024] k bf16 (l2norm)
    const unsigned short* __restrict__ knull, // [16*64] bf16
    const unsigned short* __restrict__ Vt,    // [64bh][64d][2056tok] f16
    const int* __restrict__ mask,             // [B*2048]
    unsigned short* __restrict__ ao)          // [B*2048,1024]
{
    __shared__ __bf16    Kt[2][64 * 64];
    __shared__ _Float16  Vl[2][64 * 64];
    __shared__ __align__(16) float biasLds[2][64];

    const int tid = threadIdx.x, lane = tid & 63, wave = tid >> 6;
    const int quad = lane >> 4, l15 = lane & 15;
    const int bh = blockIdx.x;                 // (b,h): K/V sharers same XCD
    const int b = bh >> 4, h = bh & 15;
    const int mbase = blockIdx.y * 128 + wave * 32;
    const size_t rowoff = (size_t)b * 2048;

    bf16x8 qf[2][2];                           // B-operand fragments
#pragma unroll
    for (int rg = 0; rg < 2; ++rg)
#pragma unroll
        for (int ks = 0; ks < 2; ++ks)
            qf[rg][ks] = *(const bf16x8*)
                &qn[((rowoff + mbase + rg * 16 + l15) << 10) + (h << 6) + ks * 32 + quad * 8];

    const int t8  = lane >> 3;
    const int w7  = lane & 7;
    const int ksc = (w7 ^ t8) << 3;            // (r&7)==t8 since base%8==0
    const size_t vrow0 = ((size_t)bh << 6);    // first VtG row of this (b,h)

    const int r0v = wave * 16 + t8;            // LDS row (p=0) = V d-row
    const int r1v = wave * 16 + 8 + t8;        // LDS row (p=1)
    auto Tof = [](int r) {
        return ((r >> 5) << 5) | (((r >> 2) & 3) << 3)
             | (((r >> 4) & 1) << 2) | (r & 3);
    };
    const int T0 = Tof(r0v), T1 = Tof(r1v);    // T1 != 0 always

    // strength-reduced staging pointers (point at NEXT tile to issue)
    const unsigned short* kp0 = kvK + ((rowoff + T0) << 10) + (h << 6) + ksc;
    const unsigned short* kp1 = kvK + ((rowoff + T1) << 10) + (h << 6) + ksc;
    const unsigned short* vp0 = Vt + (vrow0 + r0v) * 2056 + ((w7 ^ t8) << 3);
    const unsigned short* vp1 = Vt + (vrow0 + r1v) * 2056 + ((w7 ^ t8) << 3);

    auto issueFast = [&](int bf) {
        gl_lds16(kp0, &Kt[bf][(wave * 16) * 64]);
        gl_lds16(kp1, &Kt[bf][(wave * 16 + 8) * 64]);
        gl_lds16(vp0, &Vl[bf][(wave * 16) * 64]);
        gl_lds16(vp1, &Vl[bf][(wave * 16 + 8) * 64]);
        kp0 += 65536; kp1 += 65536;            // 64 tokens * 1024 halfs
        vp0 += 64; vp1 += 64;                  // 8 granules
    };
    auto issue32 = [&](int bf) {               // tokens 2048..2111
        const unsigned short* kc =
            kvK + ((rowoff + 2047) << 10) + (h << 6) + ksc;   // finite clamp
        const unsigned short* s0 = (T0 == 0) ? knull + (h << 6) + ksc : kc;
        gl_lds16(s0, &Kt[bf][(wave * 16) * 64]);
        gl_lds16(kc, &Kt[bf][(wave * 16 + 8) * 64]);
        gl_lds16(Vt + (vrow0 + r0v) * 2056 + 2048, &Vl[bf][(wave * 16) * 64]);
        gl_lds16(Vt + (vrow0 + r1v) * 2056 + 2048, &Vl[bf][(wave * 16 + 8) * 64]);
    };
    auto biasFor = [&](int nt) -> float {      // wave 0 only
        int j = (nt << 6) + lane;
        float bv = -512.f;
        if (j < 2048) { if (mask[(b << 11) + j] != 0) bv = 0.f; }
        else if (j == 2048) bv = 0.f;
        return bv;
    };

    const uintv4 onesu = { 0x3c003c00u, 0x3c003c00u, 0x3c003c00u, 0x3c003c00u };
    const f16x8 ones = __builtin_bit_cast(f16x8, onesu);

    f32x4 O[2][4] = {};
    f32x4 rsacc[2] = {};

    issueFast(0);
    float bcur = 0.f;
    if (wave == 0) bcur = biasFor(0);

    for (int nt = 0; nt < 33; ++nt) {
        const int buf = nt & 1;
        if (wave == 0) biasLds[buf][lane] = bcur;
        __syncthreads();   // drains gl_lds(nt); bias(nt) visible; prev buf free
        if (nt < 31) {     // issue AFTER barrier: overlaps compute below
            issueFast(buf ^ 1);
            if (wave == 0) bcur = biasFor(nt + 1);
        } else if (nt == 31) {
            issue32(buf ^ 1);
            if (wave == 0) bcur = biasFor(32);
        }

#pragma unroll
        for (int g = 0; g < 2; ++g) {
            // --- QK^T: only one kf pair (8 VGPRs) live at a time ---
            float4 b0 = *(const float4*)&biasLds[buf][(g << 5) + (quad << 3)];
            float4 b1 = *(const float4*)&biasLds[buf][(g << 5) + (quad << 3) + 4];
            f32x4 s[2][2];
#pragma unroll
            for (int rg = 0; rg < 2; ++rg) {
                s[rg][0] = f32x4{ b0.x, b0.y, b0.z, b0.w };
                s[rg][1] = f32x4{ b1.x, b1.y, b1.z, b1.w };
            }
#pragma unroll
            for (int t = 0; t < 2; ++t) {
                const __bf16* kb = &Kt[buf][((g * 2 + t) * 16 + l15) * 64];
                bf16x8 k0 = *(const bf16x8*)&kb[(quad ^ (l15 & 7)) << 3];
                bf16x8 k1 = *(const bf16x8*)&kb[((4 + quad) ^ (l15 & 7)) << 3];
#pragma unroll
                for (int rg = 0; rg < 2; ++rg) {
                    s[rg][t] = mfma16(k0, qf[rg][0], s[rg][t]);
                    s[rg][t] = mfma16(k1, qf[rg][1], s[rg][t]);
                }
            }
            // --- V fragments: one b128 each, XOR-swizzled slot ---
            f16x8 vf8[4];
#pragma unroll
            for (int dt = 0; dt < 4; ++dt)
                vf8[dt] = *(const f16x8*)
                    &Vl[buf][(dt * 16 + l15) * 64
                             + ((((g << 2) + quad) ^ (l15 & 7)) << 3)];
            // --- exp2 + pack + PV (+ denominator via ones-MFMA) ---
#pragma unroll
            for (int rg = 0; rg < 2; ++rg) {
                float e0 = __builtin_amdgcn_exp2f(s[rg][0][0]);
                float e1 = __builtin_amdgcn_exp2f(s[rg][0][1]);
                float e2 = __builtin_amdgcn_exp2f(s[rg][0][2]);
                float e3 = __builtin_amdgcn_exp2f(s[rg][0][3]);
                float e4 = __builtin_amdgcn_exp2f(s[rg][1][0]);
                float e5 = __builtin_amdgcn_exp2f(s[rg][1][1]);
                float e6 = __builtin_amdgcn_exp2f(s[rg][1][2]);
                float e7 = __builtin_amdgcn_exp2f(s[rg][1][3]);
                uintv4 pu = { pk16(e0, e1), pk16(e2, e3),
                              pk16(e4, e5), pk16(e6, e7) };
                f16x8 p = __builtin_bit_cast(f16x8, pu);
                rsacc[rg] = mfma16h(p, ones, rsacc[rg]);
#pragma unroll
                for (int dt = 0; dt < 4; ++dt)
                    O[rg][dt] = mfma16h(p, vf8[dt], O[rg][dt]);
            }
        }
    }

    // rsacc[rg][r] = denom for q-row rg*16 + quad*4 + r (same lane as O rows)
#pragma unroll
    for (int rg = 0; rg < 2; ++rg) {
        float inv[4];
#pragma unroll
        for (int r = 0; r < 4; ++r) inv[r] = 1.f / rsacc[rg][r];
#pragma unroll
        for (int dt = 0; dt < 4; ++dt) {
            size_t base = ((rowoff + mbase + rg * 16 + quad * 4) << 10)
                        + (h << 6) + dt * 16 + l15;
#pragma unroll
            for (int r = 0; r < 4; ++r)
                ao[base + ((size_t)r << 10)] = f2b(O[rg][dt][r] * inv[r]);
        }
    }
}

// ---------------------------------------------------------------------------
extern "C" void kernel_launch(void* const* d_in, const int* in_sizes, int n_in,
                              void* d_out, int out_size, void* d_ws, size_t ws_size,
                              hipStream_t stream)
{
    const float* x       = (const float*)d_in[0];
    const int*   mask    = (const int*)d_in[1];
    const float* gamma   = (const float*)d_in[2];
    const float* null_kv = (const float*)d_in[3];
    const float* Wq      = (const float*)d_in[4];
    const float* Wkv     = (const float*)d_in[5];
    const float* q_scale = (const float*)d_in[6];
    const float* k_scale = (const float*)d_in[7];
    const float* Wout    = (const float*)d_in[8];

    // Workspace map (~70.07 MiB; ao aliases xn; WoutT lives in the dead q
    // buffer, written by a transpose launched AFTER attn):
    //   0        xn/ao    16 MiB
    //   16 MiB   q        16 MiB   (post-attn: first 2 MiB reused as WoutT)
    //   32 MiB   kvK      16 MiB   [tok][1024] bf16
    //   48 MiB   VtG      16.0625 MiB = 4096 rows * 4112 B ([bh][d][2056] f16)
    //   +VtG     WqkvT    6 MiB    [3072][1024] bf16 (Wq rows 0..1023,
    //                              Wkv K rows 1024..2047, V rows 2048..3071)
    //   +6 MiB   knull    2 KiB
    char* ws = (char*)d_ws;
    const size_t VTG_OFF   = (size_t)48u << 20;
    const size_t VTG_SIZE  = (size_t)4096 * 4112;
    const size_t WQKV_OFF  = VTG_OFF + VTG_SIZE;
    const size_t WQKV_SIZE = (size_t)3072 * 1024 * 2;
    unsigned short* xn    = (unsigned short*)(ws);
    unsigned short* ao    = xn;                                    // reuse
    unsigned short* q     = (unsigned short*)(ws + ((size_t)16u << 20));
    unsigned short* WoutT = q;                                     // post-attn
    unsigned short* kvK   = (unsigned short*)(ws + ((size_t)32u << 20));
    unsigned short* VtG   = (unsigned short*)(ws + VTG_OFF);
    unsigned short* WqkvT = (unsigned short*)(ws + WQKV_OFF);
    unsigned short* knull = (unsigned short*)(ws + WQKV_OFF + WQKV_SIZE);

    // prep: LN (first) + Wq/Wkv transposes (last, L2-hot for QKV) + nullkv
    prep_kernel<<<dim3(11268), dim3(32, 8), 0, stream>>>(
        x, gamma, Wq, Wkv, null_kv, k_scale, xn, WqkvT, knull, VtG);

    // fused QKV projection, role-ordered 1-D grid with per-role XCD-chunked
    // tile swizzle: Q (0..511) first, K, then V last -> K/V freshest for attn
    gemm_bt<0><<<dim3(1536), 256, 0, stream>>>(xn, WqkvT, q, kvK, VtG,
                                               q_scale, k_scale, 1024);

    attn_kernel<<<dim3(64, 16), 256, 0, stream>>>(q, kvK, knull, VtG, mask, ao);

    // q is dead now; put WoutT there and run the out-projection
    transpose_f2b<<<dim3(32, 32), dim3(32, 8), 0, stream>>>(Wout, WoutT, 1024, 1024);

    gemm_bt<2><<<dim3(512), 256, 0, stream>>>(ao, WoutT, d_out, nullptr, nullptr,
                                              nullptr, nullptr, 1024);
}

// Round 11
// 252.341 us; speedup vs baseline: 1.0228x; 1.0116x over previous
//
#include <hip/hip_runtime.h>
#include <hip/hip_bf16.h>
#include <stdint.h>

// ---------------------------------------------------------------------------
// fp32 inputs; mask int32; fp32 output. Internal pipeline bf16/f16.
// prep (LN + Wq/Wkv transposes + nullkv) -> gemm_qk8 (256^2 8-phase, Q+K)
//   -> gemm_bt<0> (V role only, 128^2 2-phase) -> attn (+WoutT transpose
//   folded into 64 extra blocks writing dead WqkvT) -> out proj. 5 dispatches.
// R20: 8-phase 256^2 schedule for Q+K, derived + verified by constraint
//   analysis: half-tile = M-half (128x64); per K-tile: B-halves die after
//   its phase 1 (bfv[4][2] read once), A-halves after phase 4. Stage
//   rotation (iter j): ph1 slot1.A0<-kt(2j+1), ph2 slot1.A1, ph3/4
//   slot0.B0/B1<-kt(2j+2), ph5/6 slot0.A0/A1, ph7/8 slot1.B0/B1<-kt(2j+3).
//   Counted s_waitcnt vmcnt(4) ONLY at phases 4 and 8 (keeps newest 2
//   half-tiles in flight; retires everything the next 4 phases read).
//   Q+K shape = 256 blocks = exactly 1/CU (no tail; full QKV at 256^2 would
//   be 384 = 1.5 passes). 512 thr / 8 waves (2Mx4N) / 128 KiB dyn LDS /
//   64 MFMA per barrier-pair (2x the 128^2 kernel). V stays on the proven
//   128^2 kernel (role offset), launched after qk8 -> K/V L2-fresh for attn.
// R19: counted vmcnt in 128^2 GEMM (kept for V + out-proj).
// R16/R18: XCD-chunked swizzle; prep merge. Full history in git.
// ---------------------------------------------------------------------------

using f32x4  = __attribute__((ext_vector_type(4))) float;
using bf16x8 = __attribute__((ext_vector_type(8))) __bf16;
using f16x8  = __attribute__((ext_vector_type(8))) _Float16;
using uintv4 = __attribute__((ext_vector_type(4))) unsigned int;

__device__ __forceinline__ unsigned short f2b(float f) {
    unsigned u = __float_as_uint(f);
    u += 0x7fffu + ((u >> 16) & 1u);   // RNE
    return (unsigned short)(u >> 16);
}
__device__ __forceinline__ unsigned short f2h(float f) {   // RNE f32->f16
    return __builtin_bit_cast(unsigned short, (_Float16)f);
}
__device__ __forceinline__ f32x4 mfma16(bf16x8 a, bf16x8 b, f32x4 c) {
    return __builtin_amdgcn_mfma_f32_16x16x32_bf16(a, b, c, 0, 0, 0);
}
__device__ __forceinline__ f32x4 mfma16h(f16x8 a, f16x8 b, f32x4 c) {
    return __builtin_amdgcn_mfma_f32_16x16x32_f16(a, b, c, 0, 0, 0);
}
// packed f32x2 -> f16x2 (RTZ), returned as the raw 32-bit pattern
__device__ __forceinline__ unsigned pk16(float a, float b) {
    return __builtin_bit_cast(unsigned, __builtin_amdgcn_cvt_pkrtz(a, b));
}
// async global->LDS, 16B/lane; LDS dst = wave-uniform base + lane*16
__device__ __forceinline__ void gl_lds16(const void* g, void* l) {
    __builtin_amdgcn_global_load_lds(
        (const __attribute__((address_space(1))) unsigned int*)g,
        (__attribute__((address_space(3))) unsigned int*)l, 16, 0, 0);
}

// ---- prep: LN (8192) + Wq/Wkv transposes (3072, LAST for L2) + nullkv -----
__global__ __launch_bounds__(256) void prep_kernel(
    const float* __restrict__ x, const float* __restrict__ gamma,
    const float* __restrict__ Wq, const float* __restrict__ Wkv,
    const float* __restrict__ null_kv, const float* __restrict__ k_scale,
    unsigned short* __restrict__ xn,
    unsigned short* __restrict__ WqkvT, unsigned short* __restrict__ knull,
    unsigned short* __restrict__ Vt)
{
    __shared__ unsigned short t[32][33];
    __shared__ float ps[4], ps2[4], sh[2];
    const int bid = blockIdx.x;
    const int flat = threadIdx.x + threadIdx.y * 32;

    if (bid < 8192) {                          // ---- LayerNorm row ----
        int row = bid, tid = flat;
        int wave = tid >> 6, lane = tid & 63;
        float4 raw = *(const float4*)(x + ((size_t)row << 10) + (tid << 2));
        float v[4] = { raw.x, raw.y, raw.z, raw.w };
        float s  = v[0] + v[1] + v[2] + v[3];
        float s2 = v[0]*v[0] + v[1]*v[1] + v[2]*v[2] + v[3]*v[3];
#pragma unroll
        for (int off = 1; off < 64; off <<= 1) {
            s  += __shfl_xor(s, off);
            s2 += __shfl_xor(s2, off);
        }
        if (lane == 0) { ps[wave] = s; ps2[wave] = s2; }
        __syncthreads();
        if (tid == 0) {
            float S  = ps[0] + ps[1] + ps[2] + ps[3];
            float S2 = ps2[0] + ps2[1] + ps2[2] + ps2[3];
            float mu  = S * (1.f / 1024.f);
            float var = S2 * (1.f / 1024.f) - mu * mu;
            sh[0] = mu; sh[1] = rsqrtf(var + 1e-5f);
        }
        __syncthreads();
        float mu = sh[0], rstd = sh[1];
        float4 g4 = *(const float4*)(gamma + (tid << 2));
        float g[4] = { g4.x, g4.y, g4.z, g4.w };
        unsigned short o[4];
#pragma unroll
        for (int i = 0; i < 4; ++i) o[i] = f2b((v[i] - mu) * rstd * g[i]);
        uint2 out;
        out.x = (unsigned)o[0] | ((unsigned)o[1] << 16);
        out.y = (unsigned)o[2] | ((unsigned)o[3] << 16);
        *(uint2*)(xn + ((size_t)row << 10) + (tid << 2)) = out;
        return;
    }

    const int bid2 = bid - 8192;
    if (bid2 < 3072) {                         // ---- weight transpose ----
        const float* in; unsigned short* out; int C, bx, by;
        if (bid2 < 1024) { in = Wq;  out = WqkvT;              C = 1024;
                           bx = bid2 & 31;  by = bid2 >> 5; }
        else             { int l = bid2 - 1024;
                           in = Wkv; out = WqkvT + (1u << 20); C = 2048;
                           bx = l & 63;     by = l >> 6; }
        int tx = threadIdx.x, ty = threadIdx.y;   // (32,8)
        int c = bx * 32 + tx;
#pragma unroll
        for (int i = 0; i < 4; ++i) {
            int r = by * 32 + ty + i * 8;
            t[ty + i * 8][tx] = f2b(in[(size_t)r * C + c]);
        }
        __syncthreads();
        int r2 = by * 32 + tx;
#pragma unroll
        for (int i = 0; i < 4; ++i) {
            int c2 = bx * 32 + ty + i * 8;
            out[(size_t)c2 * 1024 + r2] = t[tx][ty + i * 8];
        }
        return;
    }

    // ---- nullkv (4 blocks) ----
    const int nb = bid2 - 3072;
    int wave = flat >> 6, lane = flat & 63;
    int h = nb * 4 + wave;
    int idx = (h << 6) + lane;
    float kvl = null_kv[idx];
    float ss = kvl * kvl;
#pragma unroll
    for (int off = 1; off < 64; off <<= 1) ss += __shfl_xor(ss, off);
    knull[idx] = f2b(kvl * rsqrtf(ss + 1e-12f) * k_scale[lane]);
    unsigned short vn = f2h(null_kv[1024 + idx]);
#pragma unroll
    for (int b = 0; b < 4; ++b)
        Vt[((size_t)(((b << 4) + h) << 6) + lane) * 2056 + 2048] = vn;
    int tt = nb * 256 + flat;                     // 0..1023
#pragma unroll
    for (int rr = 0; rr < 4; ++rr) {
        size_t row = (size_t)tt * 4 + rr;
#pragma unroll
        for (int c = 0; c < 7; ++c)
            Vt[row * 2056 + 2049 + c] = 0;
    }
}

// ---- gemm_qk8: C=A[8192,1024]*Bt^T, 256x256 tile, BK=64, 8-phase -------
// 512 thr / 8 waves (2Mx4N, per-wave 128x64). LDS [2 slot][2 Mhalf][128][64]
// for A and B (128 KiB dynamic). Granule swizzle: slot g^(row&7) via
// pre-swizzled global source (same proven pattern as the 128^2 kernel).
// Schedule per iteration j (K-tiles 2j in slot0, 2j+1 in slot1):
//   ph(t,q): [q==0: read bfv[4][2] (8xb128)] read af[2][2] (4xb128);
//            stage one half-tile; [ph4,ph8: vmcnt(4)]; barrier; lgkmcnt(0);
//            16 MFMA; barrier.
//   stages: ph1 s1.A0<-kt(2j+1) ph2 s1.A1 ph3 s0.B0<-kt(2j+2) ph4 s0.B1
//           ph5 s0.A0 ph6 s0.A1 ph7 s1.B0<-kt(2j+3) ph8 s1.B1
// RAW/WAR verified: vmcnt(4) at ph4 retires {s1.A0,s1.A1,prev s1.B0/B1}
// before ph5-8 read slot1; at ph8 retires {s0.B0,B1,A0,A1} before next
// iter reads slot0. Roles: bid<128 Q, else K (256 blocks = 1/CU exactly).
__global__ __launch_bounds__(512, 2) void gemm_qk8(
    const unsigned short* __restrict__ A,
    const unsigned short* __restrict__ Bt,
    unsigned short* __restrict__ Cq,
    unsigned short* __restrict__ Ck,
    const float* __restrict__ qs, const float* __restrict__ ks)
{
    extern __shared__ __bf16 sm8[];          // 65536 halfs = 128 KiB
    __bf16* As = sm8;                        // [2][2][128][64]
    __bf16* Bs = sm8 + 32768;

    const int tid = threadIdx.x, lane = tid & 63, wave = tid >> 6;
    const int quad = lane >> 4, l15 = lane & 15;
    const int bid = blockIdx.x;
    const int role = bid >> 7;               // 0=Q 1=K
    const int local = bid & 127;
    const int swz = ((local & 7) << 4) | (local >> 3);   // XCD-chunked
    const int m0 = (swz >> 2) * 256;
    const int n0 = role * 1024 + (swz & 3) * 256;
    const int wm = (wave >> 2) * 128;        // 0 | 128
    const int wn = (wave & 3) * 64;
    f32x4 acc[8][4] = {};

    // staging: wave covers 16 rows of a 128-row half (2 gl_lds x 8 rows);
    // lane: row8 = lane>>3, source granule (lane&7)^row8 (pre-swizzle).
    const int r8l = lane >> 3;
    const int sgr = ((lane & 7) ^ r8l) << 3;             // halfs
    const unsigned short* pA = A  + (size_t)(m0 + wave * 16 + r8l) * 1024 + sgr;
    const unsigned short* pB = Bt + (size_t)(n0 + wave * 16 + r8l) * 1024 + sgr;
    const int ldsw = (wave * 16) * 64;

    auto stgA = [&](int slot, int half, int kt) {
        __bf16* d = As + slot * 16384 + half * 8192 + ldsw;
        const unsigned short* s = pA + (size_t)(half * 128) * 1024 + kt * 64;
        gl_lds16(s, d);
        gl_lds16(s + (size_t)8 * 1024, d + 8 * 64);
    };
    auto stgB = [&](int slot, int half, int kt) {
        __bf16* d = Bs + slot * 16384 + half * 8192 + ldsw;
        const unsigned short* s = pB + (size_t)(half * 128) * 1024 + kt * 64;
        gl_lds16(s, d);
        gl_lds16(s + (size_t)8 * 1024, d + 8 * 64);
    };

    const int ahalf = wm >> 7;               // this wave's A M-half
    const int bhalf = wn >> 7;               // this wave's B M-half
    const int brow  = (wn & 64);             // row base within B half
    bf16x8 bfv[4][2];

    auto phase = [&](int slot, int q, auto stager, bool dovm) {
        if (q == 0) {
#pragma unroll
            for (int j = 0; j < 4; ++j)
#pragma unroll
                for (int kk = 0; kk < 2; ++kk)
                    bfv[j][kk] = *(const bf16x8*)&Bs[slot * 16384 + bhalf * 8192
                        + (brow + j * 16 + l15) * 64
                        + ((((kk << 2) + quad) ^ (l15 & 7)) << 3)];
        }
        bf16x8 af[2][2];
#pragma unroll
        for (int ii = 0; ii < 2; ++ii)
#pragma unroll
            for (int kk = 0; kk < 2; ++kk)
                af[ii][kk] = *(const bf16x8*)&As[slot * 16384 + ahalf * 8192
                    + ((q * 2 + ii) * 16 + l15) * 64
                    + ((((kk << 2) + quad) ^ (l15 & 7)) << 3)];
        stager();
        if (dovm) asm volatile("s_waitcnt vmcnt(4)" ::: "memory");
        __builtin_amdgcn_s_barrier();
        asm volatile("s_waitcnt lgkmcnt(0)" ::: "memory");
        __builtin_amdgcn_sched_barrier(0);
#pragma unroll
        for (int ii = 0; ii < 2; ++ii)
#pragma unroll
            for (int kk = 0; kk < 2; ++kk)
#pragma unroll
                for (int j = 0; j < 4; ++j)
                    acc[q * 2 + ii][j] =
                        mfma16(af[ii][kk], bfv[j][kk], acc[q * 2 + ii][j]);
        __builtin_amdgcn_sched_barrier(0);
        __builtin_amdgcn_s_barrier();
    };

    // prologue: kt0 {B0,B1,A0,A1} -> slot0; kt1 {B0,B1} -> slot1
    stgB(0, 0, 0); stgB(0, 1, 0); stgA(0, 0, 0); stgA(0, 1, 0);
    stgB(1, 0, 1); stgB(1, 1, 1);
    asm volatile("s_waitcnt vmcnt(4)" ::: "memory");     // kt0 complete
    __builtin_amdgcn_s_barrier();
    __builtin_amdgcn_sched_barrier(0);

    for (int it = 0; it < 8; ++it) {
        const int k1 = 2 * it + 1;           // read this iter (slot1)
        const int k2 = (2 * it + 2) & 15;    // -> slot0 (wraps on last iter)
        const int k3 = (2 * it + 3) & 15;    // -> slot1 B-halves
        phase(0, 0, [&] { stgA(1, 0, k1); }, false);
        phase(0, 1, [&] { stgA(1, 1, k1); }, false);
        phase(0, 2, [&] { stgB(0, 0, k2); }, false);
        phase(0, 3, [&] { stgB(0, 1, k2); }, true);      // vmcnt(4)
        phase(1, 0, [&] { stgA(0, 0, k2); }, false);
        phase(1, 1, [&] { stgA(0, 1, k2); }, false);
        phase(1, 2, [&] { stgB(1, 0, k3); }, false);
        phase(1, 3, [&] { stgB(1, 1, k3); }, true);      // vmcnt(4)
    }
    asm volatile("s_waitcnt vmcnt(0)" ::: "memory");     // drain wrapped tail

    // ---- epilogue: per-head l2norm (wave cols = one head) ----
    const float* sp = role ? ks : qs;
    float sc[4];
#pragma unroll
    for (int j = 0; j < 4; ++j) {
        float s = sp[j * 16 + l15];
        sc[j] = role ? s : s * (0.125f * 1.44269504088896f);
    }
    unsigned short* outp = role ? Ck : Cq;
    const int coln0 = (n0 & 1023) + wn;
#pragma unroll
    for (int i = 0; i < 8; ++i)
#pragma unroll
        for (int r = 0; r < 4; ++r) {
            float ss = 0.f;
#pragma unroll
            for (int j = 0; j < 4; ++j) ss += acc[i][j][r] * acc[i][j][r];
            ss += __shfl_xor(ss, 1); ss += __shfl_xor(ss, 2);
            ss += __shfl_xor(ss, 4); ss += __shfl_xor(ss, 8);
            float mul = rsqrtf(ss + 1e-12f);
            size_t rowbase = (size_t)(m0 + wm + i * 16 + quad * 4 + r) * 1024
                           + coln0 + l15;
#pragma unroll
            for (int j = 0; j < 4; ++j)
                outp[rowbase + j * 16] = f2b(acc[i][j][r] * mul * sc[j]);
        }
}

// ---- GEMM C=A[8192,K]*Bt[N,K]^T, 128x128 tile, BK=64, swizzled dbuf LDS --
// R19 counted-vmcnt 2-phase. Used for the V role (roleadd=2) and out-proj.
template<int MODE>
__global__ __launch_bounds__(256, 2) void gemm_bt(
    const unsigned short* __restrict__ A,
    const unsigned short* __restrict__ Bt,
    void* __restrict__ C0,
    unsigned short* __restrict__ Ck,
    unsigned short* __restrict__ Vout,
    const float* __restrict__ qs, const float* __restrict__ ks,
    int roleadd, int K)
{
    __shared__ __align__(16) unsigned char smem[65536];
    __bf16* As = (__bf16*)smem;             // [2][128][64] swizzled granules
    __bf16* Bs = (__bf16*)(smem + 32768);

    int tid = threadIdx.x, lane = tid & 63, wave = tid >> 6;
    int quad = lane >> 4, l15 = lane & 15;
    const int bid = blockIdx.x;
    const int role = (bid >> 9) + roleadd;
    const int local = bid & 511;
    const int swztile = ((local & 7) << 6) | (local >> 3);  // XCD-chunked
    int m0 = (swztile >> 3) * 128;
    int n0 = role * 1024 + (swztile & 7) * 128;
    int wm = (wave & 1) * 64, wn = (wave >> 1) * 64;
    f32x4 acc[4][4] = {};

    const int srow8 = lane >> 3;            // row-within-8 == (row&7)
    const int w7    = lane & 7;
    const int swz   = ((w7 ^ srow8) << 3);  // halfs
    const unsigned short* gA = A  + (size_t)(m0 + wave * 32 + srow8) * K + swz;
    const unsigned short* gB = Bt + (size_t)(n0 + wave * 32 + srow8) * K + swz;
    const size_t r8 = (size_t)8 * K;

    auto stage = [&](int bf) {              // 8 gl_lds per wave
        __bf16* Ab = As + bf * 8192;
        __bf16* Bb = Bs + bf * 8192;
#pragma unroll
        for (int p = 0; p < 4; ++p)
            gl_lds16(gA + p * r8, &Ab[(wave * 32 + p * 8) * 64]);
#pragma unroll
        for (int p = 0; p < 4; ++p)
            gl_lds16(gB + p * r8, &Bb[(wave * 32 + p * 8) * 64]);
        gA += 64; gB += 64;
    };

    stage(0);                               // 8 loads in flight
    const int nsteps = K >> 6;
    for (int s = 0; s < nsteps; ++s) {
        const int cur = s & 1;
        if (s + 1 < nsteps) {
            stage(cur ^ 1);                 // 16 outstanding
            asm volatile("s_waitcnt vmcnt(8)" ::: "memory");  // old tile only
        } else {
            asm volatile("s_waitcnt vmcnt(0)" ::: "memory");  // final drain
        }
        __builtin_amdgcn_s_barrier();
        __builtin_amdgcn_sched_barrier(0);
        const __bf16* Ab = As + cur * 8192;
        const __bf16* Bb = Bs + cur * 8192;
#pragma unroll
        for (int kk = 0; kk < 2; ++kk) {
            bf16x8 af[4], bfv[4];
#pragma unroll
            for (int i = 0; i < 4; ++i) {
                int row = wm + i * 16 + l15;
                int g = ((kk << 2) + quad) ^ (l15 & 7);
                af[i] = *(const bf16x8*)&Ab[row * 64 + (g << 3)];
            }
#pragma unroll
            for (int j = 0; j < 4; ++j) {
                int row = wn + j * 16 + l15;
                int g = ((kk << 2) + quad) ^ (l15 & 7);
                bfv[j] = *(const bf16x8*)&Bb[row * 64 + (g << 3)];
            }
#pragma unroll
            for (int i = 0; i < 4; ++i)
#pragma unroll
                for (int j = 0; j < 4; ++j)
                    acc[i][j] = mfma16(af[i], bfv[j], acc[i][j]);
        }
        __builtin_amdgcn_sched_barrier(0);
        __builtin_amdgcn_s_barrier();
    }

    if (MODE == 2) {
#pragma unroll
        for (int i = 0; i < 4; ++i)
#pragma unroll
            for (int j = 0; j < 4; ++j) {
                int row = m0 + wm + i * 16 + quad * 4;
                int col = n0 + wn + j * 16 + l15;
                size_t base = (size_t)row * 1024 + col;
#pragma unroll
                for (int r = 0; r < 4; ++r)
                    ((float*)C0)[base + (size_t)r * 1024] = acc[i][j][r];
            }
        return;
    }

    // ----- V epilogue (role 2): per-wave 64x64 LDS transpose -> uint2 -----
    if (n0 >= 2048) {
        unsigned short* tileL = (unsigned short*)smem + wave * 4096;
        int hv = (n0 + wn - 2048) >> 6;
        int bidx = m0 >> 11;
        int tok0w = (m0 + wm) & 2047;
        size_t vbase = (size_t)((((bidx << 4) + hv) << 6)) * 2056;
#pragma unroll
        for (int i = 0; i < 4; ++i)
#pragma unroll
            for (int j = 0; j < 4; ++j) {
                int d = j * 16 + l15;
                int tk = (i * 16 + quad * 4) ^ ((d & 7) << 3);
                unsigned u01 = (unsigned)f2h(acc[i][j][0])
                             | ((unsigned)f2h(acc[i][j][1]) << 16);
                unsigned u23 = (unsigned)f2h(acc[i][j][2])
                             | ((unsigned)f2h(acc[i][j][3]) << 16);
                *(unsigned*)&tileL[d * 64 + tk]     = u01;
                *(unsigned*)&tileL[d * 64 + tk + 2] = u23;
            }
#pragma unroll
        for (int rrr = 0; rrr < 16; ++rrr) {
            int d = rrr * 4 + quad;
            uint2 val = *(const uint2*)
                &tileL[d * 64 + ((l15 * 4) ^ ((d & 7) << 3))];
            *(uint2*)(Vout + vbase + (size_t)d * 2056 + tok0w + l15 * 4) = val;
        }
        return;
    }

    // (Q/K epilogue unused in this configuration; kept for completeness)
    const bool isQ = (n0 < 1024);
    float sc[4];
#pragma unroll
    for (int j = 0; j < 4; ++j) {
        float s = isQ ? qs[j * 16 + l15] : ks[j * 16 + l15];
        sc[j] = isQ ? s * (0.125f * 1.44269504088896f) : s;
    }
    unsigned short* outp = isQ ? (unsigned short*)C0 : Ck;
    const int coln0 = isQ ? n0 : (n0 - 1024);
#pragma unroll
    for (int i = 0; i < 4; ++i)
#pragma unroll
        for (int r = 0; r < 4; ++r) {
            float ss = 0.f;
#pragma unroll
            for (int j = 0; j < 4; ++j) ss += acc[i][j][r] * acc[i][j][r];
            ss += __shfl_xor(ss, 1); ss += __shfl_xor(ss, 2);
            ss += __shfl_xor(ss, 4); ss += __shfl_xor(ss, 8);
            float mul = rsqrtf(ss + 1e-12f);
            size_t rowbase = (size_t)(m0 + wm + i * 16 + quad * 4 + r) * 1024
                           + coln0 + wn + l15;
#pragma unroll
            for (int j = 0; j < 4; ++j)
                outp[rowbase + j * 16] = f2b(acc[i][j][r] * mul * sc[j]);
        }
}

// ---------------- attention + folded WoutT transpose -----------------------
// bid < 1024: attn block (bh = bid&63, ytile = bid>>6 — same XCD mapping as
// the old 2-D grid). bid >= 1024: 64 blocks transpose Wout f32 -> WoutT bf16
// into the DEAD WqkvT buffer (dead after the QKV GEMMs; out-proj reads it).
__global__ __launch_bounds__(256, 4) void attn_kernel(
    const unsigned short* __restrict__ qn,    // [B*2048,1024] l2norm*qs*log2e/8
    const unsigned short* __restrict__ kvK,   // [B*2048,1024] k bf16 (l2norm)
    const unsigned short* __restrict__ knull, // [16*64] bf16
    const unsigned short* __restrict__ Vt,    // [64bh][64d][2056tok] f16
    const int* __restrict__ mask,             // [B*2048]
    unsigned short* __restrict__ ao,          // [B*2048,1024]
    const float* __restrict__ Wout,           // [1024][1024] f32
    unsigned short* __restrict__ WoutT)       // -> dead WqkvT space
{
    __shared__ __bf16    Kt[2][64 * 64];
    __shared__ _Float16  Vl[2][64 * 64];
    __shared__ __align__(16) float biasLds[2][64];

    const int tid = threadIdx.x;
    if (blockIdx.x >= 1024) {                  // ---- WoutT transpose ----
        unsigned short (*t32)[33] = (unsigned short (*)[33])Kt;
        int tb = blockIdx.x - 1024;            // 0..63 -> 128x128 region
        int tx = tid & 31, ty = tid >> 5;      // (32,8)
#pragma unroll
        for (int sub = 0; sub < 16; ++sub) {
            int gx = (tb & 7) * 4 + (sub & 3);
            int gy = (tb >> 3) * 4 + (sub >> 2);
            int c = gx * 32 + tx;
            __syncthreads();                   // prev sub's readers done
#pragma unroll
            for (int i = 0; i < 4; ++i) {
                int r = gy * 32 + ty + i * 8;
                t32[ty + i * 8][tx] = f2b(Wout[(size_t)r * 1024 + c]);
            }
            __syncthreads();
            int r2 = gy * 32 + tx;
#pragma unroll
            for (int i = 0; i < 4; ++i) {
                int c2 = gx * 32 + ty + i * 8;
                WoutT[(size_t)c2 * 1024 + r2] = t32[tx][ty + i * 8];
            }
        }
        return;
    }

    const int lane = tid & 63, wave = tid >> 6;
    const int quad = lane >> 4, l15 = lane & 15;
    const int bh = blockIdx.x & 63;            // (b,h): K/V sharers same XCD
    const int b = bh >> 4, h = bh & 15;
    const int mbase = (blockIdx.x >> 6) * 128 + wave * 32;
    const size_t rowoff = (size_t)b * 2048;

    bf16x8 qf[2][2];                           // B-operand fragments
#pragma unroll
    for (int rg = 0; rg < 2; ++rg)
#pragma unroll
        for (int ks = 0; ks < 2; ++ks)
            qf[rg][ks] = *(const bf16x8*)
                &qn[((rowoff + mbase + rg * 16 + l15) << 10) + (h << 6) + ks * 32 + quad * 8];

    const int t8  = lane >> 3;
    const int w7  = lane & 7;
    const int ksc = (w7 ^ t8) << 3;            // (r&7)==t8 since base%8==0
    const size_t vrow0 = ((size_t)bh << 6);    // first VtG row of this (b,h)

    const int r0v = wave * 16 + t8;            // LDS row (p=0) = V d-row
    const int r1v = wave * 16 + 8 + t8;        // LDS row (p=1)
    auto Tof = [](int r) {
        return ((r >> 5) << 5) | (((r >> 2) & 3) << 3)
             | (((r >> 4) & 1) << 2) | (r & 3);
    };
    const int T0 = Tof(r0v), T1 = Tof(r1v);    // T1 != 0 always

    // strength-reduced staging pointers (point at NEXT tile to issue)
    const unsigned short* kp0 = kvK + ((rowoff + T0) << 10) + (h << 6) + ksc;
    const unsigned short* kp1 = kvK + ((rowoff + T1) << 10) + (h << 6) + ksc;
    const unsigned short* vp0 = Vt + (vrow0 + r0v) * 2056 + ((w7 ^ t8) << 3);
    const unsigned short* vp1 = Vt + (vrow0 + r1v) * 2056 + ((w7 ^ t8) << 3);

    auto issueFast = [&](int bf) {
        gl_lds16(kp0, &Kt[bf][(wave * 16) * 64]);
        gl_lds16(kp1, &Kt[bf][(wave * 16 + 8) * 64]);
        gl_lds16(vp0, &Vl[bf][(wave * 16) * 64]);
        gl_lds16(vp1, &Vl[bf][(wave * 16 + 8) * 64]);
        kp0 += 65536; kp1 += 65536;            // 64 tokens * 1024 halfs
        vp0 += 64; vp1 += 64;                  // 8 granules
    };
    auto issue32 = [&](int bf) {               // tokens 2048..2111
        const unsigned short* kc =
            kvK + ((rowoff + 2047) << 10) + (h << 6) + ksc;   // finite clamp
        const unsigned short* s0 = (T0 == 0) ? knull + (h << 6) + ksc : kc;
        gl_lds16(s0, &Kt[bf][(wave * 16) * 64]);
        gl_lds16(kc, &Kt[bf][(wave * 16 + 8) * 64]);
        gl_lds16(Vt + (vrow0 + r0v) * 2056 + 2048, &Vl[bf][(wave * 16) * 64]);
        gl_lds16(Vt + (vrow0 + r1v) * 2056 + 2048, &Vl[bf][(wave * 16 + 8) * 64]);
    };
    auto biasFor = [&](int nt) -> float {      // wave 0 only
        int j = (nt << 6) + lane;
        float bv = -512.f;
        if (j < 2048) { if (mask[(b << 11) + j] != 0) bv = 0.f; }
        else if (j == 2048) bv = 0.f;
        return bv;
    };

    const uintv4 onesu = { 0x3c003c00u, 0x3c003c00u, 0x3c003c00u, 0x3c003c00u };
    const f16x8 ones = __builtin_bit_cast(f16x8, onesu);

    f32x4 O[2][4] = {};
    f32x4 rsacc[2] = {};

    issueFast(0);
    float bcur = 0.f;
    if (wave == 0) bcur = biasFor(0);

    for (int nt = 0; nt < 33; ++nt) {
        const int buf = nt & 1;
        if (wave == 0) biasLds[buf][lane] = bcur;
        __syncthreads();   // drains gl_lds(nt); bias(nt) visible; prev buf free
        if (nt < 31) {     // issue AFTER barrier: overlaps compute below
            issueFast(buf ^ 1);
            if (wave == 0) bcur = biasFor(nt + 1);
        } else if (nt == 31) {
            issue32(buf ^ 1);
            if (wave == 0) bcur = biasFor(32);
        }

#pragma unroll
        for (int g = 0; g < 2; ++g) {
            // --- QK^T: only one kf pair (8 VGPRs) live at a time ---
            float4 b0 = *(const float4*)&biasLds[buf][(g << 5) + (quad << 3)];
            float4 b1 = *(const float4*)&biasLds[buf][(g << 5) + (quad << 3) + 4];
            f32x4 s[2][2];
#pragma unroll
            for (int rg = 0; rg < 2; ++rg) {
                s[rg][0] = f32x4{ b0.x, b0.y, b0.z, b0.w };
                s[rg][1] = f32x4{ b1.x, b1.y, b1.z, b1.w };
            }
#pragma unroll
            for (int t = 0; t < 2; ++t) {
                const __bf16* kb = &Kt[buf][((g * 2 + t) * 16 + l15) * 64];
                bf16x8 k0 = *(const bf16x8*)&kb[(quad ^ (l15 & 7)) << 3];
                bf16x8 k1 = *(const bf16x8*)&kb[((4 + quad) ^ (l15 & 7)) << 3];
#pragma unroll
                for (int rg = 0; rg < 2; ++rg) {
                    s[rg][t] = mfma16(k0, qf[rg][0], s[rg][t]);
                    s[rg][t] = mfma16(k1, qf[rg][1], s[rg][t]);
                }
            }
            // --- V fragments: one b128 each, XOR-swizzled slot ---
            f16x8 vf8[4];
#pragma unroll
            for (int dt = 0; dt < 4; ++dt)
                vf8[dt] = *(const f16x8*)
                    &Vl[buf][(dt * 16 + l15) * 64
                             + ((((g << 2) + quad) ^ (l15 & 7)) << 3)];
            // --- exp2 + pack + PV (+ denominator via ones-MFMA) ---
#pragma unroll
            for (int rg = 0; rg < 2; ++rg) {
                float e0 = __builtin_amdgcn_exp2f(s[rg][0][0]);
                float e1 = __builtin_amdgcn_exp2f(s[rg][0][1]);
                float e2 = __builtin_amdgcn_exp2f(s[rg][0][2]);
                float e3 = __builtin_amdgcn_exp2f(s[rg][0][3]);
                float e4 = __builtin_amdgcn_exp2f(s[rg][1][0]);
                float e5 = __builtin_amdgcn_exp2f(s[rg][1][1]);
                float e6 = __builtin_amdgcn_exp2f(s[rg][1][2]);
                float e7 = __builtin_amdgcn_exp2f(s[rg][1][3]);
                uintv4 pu = { pk16(e0, e1), pk16(e2, e3),
                              pk16(e4, e5), pk16(e6, e7) };
                f16x8 p = __builtin_bit_cast(f16x8, pu);
                rsacc[rg] = mfma16h(p, ones, rsacc[rg]);
#pragma unroll
                for (int dt = 0; dt < 4; ++dt)
                    O[rg][dt] = mfma16h(p, vf8[dt], O[rg][dt]);
            }
        }
    }

    // rsacc[rg][r] = denom for q-row rg*16 + quad*4 + r (same lane as O rows)
#pragma unroll
    for (int rg = 0; rg < 2; ++rg) {
        float inv[4];
#pragma unroll
        for (int r = 0; r < 4; ++r) inv[r] = 1.f / rsacc[rg][r];
#pragma unroll
        for (int dt = 0; dt < 4; ++dt) {
            size_t base = ((rowoff + mbase + rg * 16 + quad * 4) << 10)
                        + (h << 6) + dt * 16 + l15;
#pragma unroll
            for (int r = 0; r < 4; ++r)
                ao[base + ((size_t)r << 10)] = f2b(O[rg][dt][r] * inv[r]);
        }
    }
}

// ---------------------------------------------------------------------------
extern "C" void kernel_launch(void* const* d_in, const int* in_sizes, int n_in,
                              void* d_out, int out_size, void* d_ws, size_t ws_size,
                              hipStream_t stream)
{
    const float* x       = (const float*)d_in[0];
    const int*   mask    = (const int*)d_in[1];
    const float* gamma   = (const float*)d_in[2];
    const float* null_kv = (const float*)d_in[3];
    const float* Wq      = (const float*)d_in[4];
    const float* Wkv     = (const float*)d_in[5];
    const float* q_scale = (const float*)d_in[6];
    const float* k_scale = (const float*)d_in[7];
    const float* Wout    = (const float*)d_in[8];

    // Workspace map (~70.07 MiB; ao aliases xn; WoutT reuses WqkvT, which is
    // dead after the QKV GEMMs — written by attn's folded transpose blocks):
    //   0        xn/ao    16 MiB
    //   16 MiB   q        16 MiB
    //   32 MiB   kvK      16 MiB   [tok][1024] bf16
    //   48 MiB   VtG      16.0625 MiB ([bh][d][2056] f16)
    //   +VtG     WqkvT    6 MiB    (post-attn: first 2 MiB = WoutT)
    //   +6 MiB   knull    2 KiB
    char* ws = (char*)d_ws;
    const size_t VTG_OFF   = (size_t)48u << 20;
    const size_t VTG_SIZE  = (size_t)4096 * 4112;
    const size_t WQKV_OFF  = VTG_OFF + VTG_SIZE;
    const size_t WQKV_SIZE = (size_t)3072 * 1024 * 2;
    unsigned short* xn    = (unsigned short*)(ws);
    unsigned short* ao    = xn;                                    // reuse
    unsigned short* q     = (unsigned short*)(ws + ((size_t)16u << 20));
    unsigned short* kvK   = (unsigned short*)(ws + ((size_t)32u << 20));
    unsigned short* VtG   = (unsigned short*)(ws + VTG_OFF);
    unsigned short* WqkvT = (unsigned short*)(ws + WQKV_OFF);
    unsigned short* WoutT = WqkvT;                                 // post-QKV
    unsigned short* knull = (unsigned short*)(ws + WQKV_OFF + WQKV_SIZE);

    // allow 128 KiB dynamic LDS for gemm_qk8
    hipFuncSetAttribute((const void*)gemm_qk8,
                        hipFuncAttributeMaxDynamicSharedMemorySize, 131072);

    // prep: LN (first) + Wq/Wkv transposes (last, L2-hot for QKV) + nullkv
    prep_kernel<<<dim3(11268), dim3(32, 8), 0, stream>>>(
        x, gamma, Wq, Wkv, null_kv, k_scale, xn, WqkvT, knull, VtG);

    // Q+K projection: 256^2 8-phase, 256 blocks = exactly 1/CU
    gemm_qk8<<<dim3(256), dim3(512), 131072, stream>>>(
        xn, WqkvT, q, kvK, q_scale, k_scale);

    // V projection on the proven 128^2 2-phase kernel (role 2), last -> L2
    gemm_bt<0><<<dim3(512), 256, 0, stream>>>(xn, WqkvT, q, kvK, VtG,
                                              q_scale, k_scale, 2, 1024);

    // attn (1024 blocks) + folded WoutT transpose (64 blocks into dead WqkvT)
    attn_kernel<<<dim3(1088), 256, 0, stream>>>(q, kvK, knull, VtG, mask, ao,
                                                Wout, WoutT);

    gemm_bt<2><<<dim3(512), 256, 0, stream>>>(ao, WoutT, d_out, nullptr, nullptr,
                                              nullptr, nullptr, 0, 1024);
}